// Round 1
// baseline (235.665 us; speedup 1.0000x reference)
//
#include <hip/hip_runtime.h>
#include <hip/hip_bf16.h>
#include <math.h>

#define NVOX   884736      // 96^3 per batch
#define NBINS  64
#define NCHUNK 27648       // NVOX / 32
#define GX     384         // blocks per batch in k_main
#define NWAVETOT (GX*4)    // 1536 waves per batch; 27648/1536 = 18 chunks each
#define EPSF   1e-8f

// A = sqrt(0.5*log2(e))/sigma ; w = exp(-0.5*((xn-c)/sigma)^2) = exp2(-(A*xn - A*c)^2)
#define A_SC  8.49321957f
#define ABIN  (A_SC/63.0f)

// ws layout (float/uint indices)
#define OFF_MMIN 0          // 4 mapped uints  (img*2+b)
#define OFF_MMAX 4          // 4 mapped uints
#define OFF_J    16         // 2*4096 floats
#define OFF_PF   (16+8192)  // 2*64 floats
#define OFF_PW   (OFF_PF+128)
#define WS_END   (OFF_PW+128)

typedef __attribute__((ext_vector_type(8))) short short8;
typedef __attribute__((ext_vector_type(4))) float f32x4;

__device__ __forceinline__ unsigned fmap(float f){
  unsigned u = __float_as_uint(f);
  return (u & 0x80000000u) ? ~u : (u | 0x80000000u);
}
__device__ __forceinline__ float funmap(unsigned u){
  unsigned v = (u & 0x80000000u) ? (u & 0x7FFFFFFFu) : ~u;
  return __uint_as_float(v);
}

__global__ void k_init(unsigned* wsu, float* wsf){
  int i = blockIdx.x*blockDim.x + threadIdx.x;
  if (i < 4)      wsu[i]     = 0xFFFFFFFFu;  // min identity (mapped)
  else if (i < 8) wsu[i]     = 0u;           // max identity (mapped)
  for (int j = 16 + i; j < WS_END; j += gridDim.x*blockDim.x) wsf[j] = 0.f;
}

__global__ void k_minmax(const float* __restrict__ fixed_, const float* __restrict__ warped_,
                         unsigned* wsu){
  int slot = blockIdx.y;                       // img*2 + b
  const float* p = ((slot & 2) ? warped_ : fixed_) + (slot & 1) * NVOX;
  const float4* p4 = (const float4*)p;
  const int n4 = NVOX/4;
  float lo = 3.4e38f, hi = -3.4e38f;
  for (int i = blockIdx.x*blockDim.x + threadIdx.x; i < n4; i += gridDim.x*blockDim.x){
    float4 v = p4[i];
    lo = fminf(lo, fminf(fminf(v.x,v.y), fminf(v.z,v.w)));
    hi = fmaxf(hi, fmaxf(fmaxf(v.x,v.y), fmaxf(v.z,v.w)));
  }
  #pragma unroll
  for (int d = 1; d < 64; d <<= 1){
    lo = fminf(lo, __shfl_xor(lo, d));
    hi = fmaxf(hi, __shfl_xor(hi, d));
  }
  if ((threadIdx.x & 63) == 0){
    atomicMin(&wsu[OFF_MMIN + slot], fmap(lo));
    atomicMax(&wsu[OFF_MMAX + slot], fmap(hi));
  }
}

__global__ __launch_bounds__(256) void k_main(const float* __restrict__ fx0,
                                              const float* __restrict__ wx0,
                                              float* wsf, const unsigned* wsu){
  const int b    = blockIdx.y;
  const int lane = threadIdx.x & 63;
  const int wid  = threadIdx.x >> 6;
  const int r    = lane & 15;       // bin-within-quadrant (A row / B col)
  const int g    = lane >> 4;       // k-group: voxels 8g..8g+7

  // per-lane normalization constants (lanes 0-31: fixed, 32-63: warped)
  const int img = lane >> 5;
  const float lo = funmap(wsu[OFF_MMIN + img*2 + b]);
  const float hi = funmap(wsu[OFF_MMAX + img*2 + b]);
  const float mn = lo;
  const float sc = A_SC / (hi - lo + EPSF);

  float CQ[4];
  #pragma unroll
  for (int q = 0; q < 4; q++) CQ[q] = (float)(16*q + r) * ABIN;

  f32x4 acc[4][4];
  #pragma unroll
  for (int q = 0; q < 4; q++)
    #pragma unroll
    for (int t = 0; t < 4; t++)
      acc[q][t] = (f32x4){0.f,0.f,0.f,0.f};
  float pfa[4] = {0.f,0.f,0.f,0.f}, pwa[4] = {0.f,0.f,0.f,0.f};

  const float* fx = fx0 + b*NVOX;
  const float* wx = wx0 + b*NVOX;
  const float* src = (lane < 32) ? fx : (wx - 32);
  const int gwave = blockIdx.x*4 + wid;

  for (int c = gwave; c < NCHUNK; c += NWAVETOT){
    const int base = c * 32;
    // lane v<32 owns fixed voxel v; lane 32+v owns warped voxel v
    float x = src[base + lane];
    float u = (x - mn) * sc;
    // normalization sum S = sum_k exp2(-(u - A*c_k)^2)
    float S = 0.f;
    #pragma unroll
    for (int k = 0; k < 64; k++){
      float t = u - (float)k * ABIN;
      S += __builtin_amdgcn_exp2f(-(t*t));
    }
    float lg = -__builtin_amdgcn_logf(S + EPSF);  // log2(1/(S+eps)) folds into exp2 arg

    // distribute per-voxel (u, lg) to the lanes that build fragments
    float uf[8], lf[8], uw[8], lw[8];
    #pragma unroll
    for (int i = 0; i < 8; i++){
      int v = 8*g + i;
      uf[i] = __shfl(u,  v);
      lf[i] = __shfl(lg, v);
      uw[i] = __shfl(u,  v + 32);
      lw[i] = __shfl(lg, v + 32);
    }

    // B fragments (warped side), 4 quadrants; B[k][c]: lane 16g+c holds k=8g+i
    short8 Bf[4];
    #pragma unroll
    for (int qq = 0; qq < 4; qq++){
      #pragma unroll
      for (int i = 0; i < 8; i++){
        float t = uw[i] - CQ[qq];
        float w = __builtin_amdgcn_exp2f(__builtin_fmaf(-t, t, lw[i])); // normalized weight
        pwa[qq] += w;
        __bf16 hb = (__bf16)w;
        Bf[qq][i] = __builtin_bit_cast(short, hb);
      }
    }
    // A fragments (fixed side) per quadrant + MFMA row of 4
    #pragma unroll
    for (int q = 0; q < 4; q++){
      short8 Af;
      #pragma unroll
      for (int i = 0; i < 8; i++){
        float t = uf[i] - CQ[q];
        float w = __builtin_amdgcn_exp2f(__builtin_fmaf(-t, t, lf[i]));
        pfa[q] += w;
        __bf16 hb = (__bf16)w;
        Af[i] = __builtin_bit_cast(short, hb);
      }
      #pragma unroll
      for (int qq = 0; qq < 4; qq++)
        acc[q][qq] = __builtin_amdgcn_mfma_f32_16x16x32_bf16(Af, Bf[qq], acc[q][qq], 0, 0, 0);
    }
  }

  // marginals: sum over g-groups (lanes ^16, ^32), then lanes 0-15 commit
  #pragma unroll
  for (int q = 0; q < 4; q++){
    pfa[q] += __shfl_xor(pfa[q], 16); pfa[q] += __shfl_xor(pfa[q], 32);
    pwa[q] += __shfl_xor(pwa[q], 16); pwa[q] += __shfl_xor(pwa[q], 32);
  }
  if (lane < 16){
    #pragma unroll
    for (int q = 0; q < 4; q++){
      atomicAdd(&wsf[OFF_PF + b*64 + 16*q + r], pfa[q]);
      atomicAdd(&wsf[OFF_PW + b*64 + 16*q + r], pwa[q]);
    }
  }

  // joint: block-level LDS reduction, then global atomics
  __shared__ float jl[64*64];
  for (int i = threadIdx.x; i < 4096; i += 256) jl[i] = 0.f;
  __syncthreads();
  // C/D layout (m89-verified): col = lane&15, row = (lane>>4)*4 + reg
  #pragma unroll
  for (int q = 0; q < 4; q++)
    #pragma unroll
    for (int qq = 0; qq < 4; qq++)
      #pragma unroll
      for (int j = 0; j < 4; j++){
        int row = 16*q + 4*g + j;
        int col = 16*qq + r;
        atomicAdd(&jl[row*64 + col], acc[q][qq][j]);
      }
  __syncthreads();
  for (int i = threadIdx.x; i < 4096; i += 256)
    atomicAdd(&wsf[OFF_J + b*4096 + i], jl[i]);
}

__global__ void k_final(const float* wsf, float* out){
  __shared__ double red[256];
  const int tid = threadIdx.x;
  double mi_sum = 0.0;
  for (int b = 0; b < 2; b++){
    const float* J  = wsf + OFF_J  + b*4096;
    const float* PF = wsf + OFF_PF + b*64;
    const float* PW = wsf + OFF_PW + b*64;
    // total of p_joint_raw = sum(J)/N
    double ts = 0.0;
    for (int i = tid; i < 4096; i += 256) ts += (double)J[i];
    red[tid] = ts; __syncthreads();
    for (int s = 128; s > 0; s >>= 1){ if (tid < s) red[tid] += red[tid+s]; __syncthreads(); }
    double tot = red[0] / (double)NVOX;
    __syncthreads();
    double part = 0.0;
    for (int i = tid; i < 4096; i += 256){
      int k = i >> 6, l = i & 63;
      double pj = ((double)J[i] / (double)NVOX) / (tot + 1e-8);
      double pp = ((double)PF[k] / (double)NVOX) * ((double)PW[l] / (double)NVOX);
      part += pj * log((pj + 1e-8) / (pp + 1e-8));
    }
    red[tid] = part; __syncthreads();
    for (int s = 128; s > 0; s >>= 1){ if (tid < s) red[tid] += red[tid+s]; __syncthreads(); }
    mi_sum += red[0];
    __syncthreads();
  }
  if (tid == 0) out[0] = (float)(-(mi_sum * 0.5));
}

extern "C" void kernel_launch(void* const* d_in, const int* in_sizes, int n_in,
                              void* d_out, int out_size, void* d_ws, size_t ws_size,
                              hipStream_t stream) {
  const float* fixed_  = (const float*)d_in[0];
  const float* warped_ = (const float*)d_in[1];
  float*    wsf = (float*)d_ws;
  unsigned* wsu = (unsigned*)d_ws;
  float*    out = (float*)d_out;

  hipLaunchKernelGGL(k_init,   dim3(33),     dim3(256), 0, stream, wsu, wsf);
  hipLaunchKernelGGL(k_minmax, dim3(128, 4), dim3(256), 0, stream, fixed_, warped_, wsu);
  hipLaunchKernelGGL(k_main,   dim3(GX, 2),  dim3(256), 0, stream, fixed_, warped_, wsf, wsu);
  hipLaunchKernelGGL(k_final,  dim3(1),      dim3(256), 0, stream, wsf, out);
}

// Round 4
// 202.962 us; speedup vs baseline: 1.1611x; 1.1611x over previous
//
#include <hip/hip_runtime.h>
#include <hip/hip_bf16.h>
#include <math.h>

#define NVOX   884736      // 96^3 per batch
#define NBINS  64
#define NCHUNK 27648       // NVOX / 32
#define GX     512         // blocks per batch in k_main
#define NWAVETOT (GX*4)
#define EPSF   1e-8f

// w = exp(-0.5*((xn-c)/sigma)^2) = exp2(-(A*xn - A*c)^2),  A = sqrt(0.5*log2(e))/sigma
#define A_SC  8.49321957f
#define ABIN  (A_SC/63.0f)

// fixed-point scale for deterministic integer accumulation
#define FSCALE 1073741824.0f   // 2^30
#define DSCALE (1.0/1073741824.0)

typedef __attribute__((ext_vector_type(8))) short short8;
typedef __attribute__((ext_vector_type(4))) float f32x4;
typedef unsigned long long u64;

#define EXP2(x) __builtin_amdgcn_exp2f(x)

// ws layout: bytes [0,32): 8 u32 minmax header; byte 64+: u64 region
// J64: 2*4096, then PF64: 2*64, PW64: 2*64  (total 8448 u64)
#define NJ64 8448

__device__ __forceinline__ unsigned fmap(float f){
  unsigned u = __float_as_uint(f);
  return (u & 0x80000000u) ? ~u : (u | 0x80000000u);
}
__device__ __forceinline__ float funmap(unsigned u){
  unsigned v = (u & 0x80000000u) ? (u & 0x7FFFFFFFu) : ~u;
  return __uint_as_float(v);
}
__device__ __forceinline__ short tobf(float w){
  __bf16 hb = (__bf16)w;
  return __builtin_bit_cast(short, hb);
}

__global__ void k_init(unsigned* wsu, u64* w64){
  int i = blockIdx.x*blockDim.x + threadIdx.x;
  if (i < 4)      wsu[i] = 0xFFFFFFFFu;  // min identity (mapped)
  else if (i < 8) wsu[i] = 0u;           // max identity (mapped)
  for (int j = i; j < NJ64; j += gridDim.x*blockDim.x) w64[j] = 0ull;
}

__global__ void k_minmax(const float* __restrict__ fixed_, const float* __restrict__ warped_,
                         unsigned* wsu){
  int slot = blockIdx.y;                       // img*2 + b
  const float* p = ((slot & 2) ? warped_ : fixed_) + (slot & 1) * NVOX;
  const float4* p4 = (const float4*)p;
  const int n4 = NVOX/4;
  float lo = 3.4e38f, hi = -3.4e38f;
  for (int i = blockIdx.x*blockDim.x + threadIdx.x; i < n4; i += gridDim.x*blockDim.x){
    float4 v = p4[i];
    lo = fminf(lo, fminf(fminf(v.x,v.y), fminf(v.z,v.w)));
    hi = fmaxf(hi, fmaxf(fmaxf(v.x,v.y), fmaxf(v.z,v.w)));
  }
  #pragma unroll
  for (int d = 1; d < 64; d <<= 1){
    lo = fminf(lo, __shfl_xor(lo, d));
    hi = fmaxf(hi, __shfl_xor(hi, d));
  }
  if ((threadIdx.x & 63) == 0){
    atomicMin(&wsu[0 + slot], fmap(lo));
    atomicMax(&wsu[4 + slot], fmap(hi));
  }
}

__global__ __launch_bounds__(256) void k_main(const float* __restrict__ fx0,
                                              const float* __restrict__ wx0,
                                              u64* __restrict__ J64,
                                              u64* __restrict__ PF64,
                                              u64* __restrict__ PW64,
                                              const unsigned* __restrict__ wsu){
  const int b    = blockIdx.y;
  const int lane = threadIdx.x & 63;
  const int wid  = threadIdx.x >> 6;
  const int r    = lane & 15;       // bin-within-quadrant (A row / B col)
  const int g    = lane >> 4;       // k-group: voxels 8g..8g+7

  // per-lane normalization constants (lanes 0-31: fixed, 32-63: warped)
  const int img = lane >> 5;
  const float lo = funmap(wsu[0 + img*2 + b]);
  const float hi = funmap(wsu[4 + img*2 + b]);
  const float mn = lo;
  const float sc = A_SC / (hi - lo + EPSF);

  const float H = ABIN;
  float CQ[4];
  #pragma unroll
  for (int q = 0; q < 4; q++) CQ[q] = (float)(16*q + r) * H;

  f32x4 acc[4][4];
  #pragma unroll
  for (int q = 0; q < 4; q++)
    #pragma unroll
    for (int t = 0; t < 4; t++)
      acc[q][t] = (f32x4){0.f,0.f,0.f,0.f};
  float pfa[4] = {0.f,0.f,0.f,0.f}, pwa[4] = {0.f,0.f,0.f,0.f};

  const float* fx = fx0 + b*NVOX;
  const float* wx = wx0 + b*NVOX;
  const float* src = (lane < 32) ? fx : (wx - 32);
  const int gwave = blockIdx.x*4 + wid;

  // software-pipelined voxel load
  float x = src[gwave*32 + lane];
  for (int c = gwave; c < NCHUNK; c += NWAVETOT){
    const float xc = x;
    const int cn = c + NWAVETOT;
    if (cn < NCHUNK) x = src[cn*32 + lane];

    const float u = (xc - mn) * sc;

    // ---- S = sum_k exp2(-(u - k*H)^2): ROUND-1 term form (t first, then square),
    //      4 independent accumulators for ILP (reassociation only) ----
    float S0=0.f, S1=0.f, S2=0.f, S3=0.f;
    #pragma unroll
    for (int k = 0; k < 64; k += 4){
      float t0 = u - (float)(k+0)*H; S0 += EXP2(-(t0*t0));
      float t1 = u - (float)(k+1)*H; S1 += EXP2(-(t1*t1));
      float t2 = u - (float)(k+2)*H; S2 += EXP2(-(t2*t2));
      float t3 = u - (float)(k+3)*H; S3 += EXP2(-(t3*t3));
    }
    const float S = (S0+S1)+(S2+S3);
    const float lg = -__builtin_amdgcn_logf(S + EPSF);  // log2(1/(S+eps))

    // distribute per-voxel (u, lg) to fragment-builder lanes
    float uf[8], lf[8], uw[8], lw[8];
    #pragma unroll
    for (int i = 0; i < 8; i++){
      int v = 8*g + i;
      uf[i] = __shfl(u,  v);
      lf[i] = __shfl(lg, v);
      uw[i] = __shfl(u,  v + 32);
      lw[i] = __shfl(lg, v + 32);
    }

    // B fragments (warped), 4 quadrants — exact round-1 per-weight form
    short8 Bf[4];
    #pragma unroll
    for (int qq = 0; qq < 4; qq++){
      #pragma unroll
      for (int i = 0; i < 8; i++){
        float t = uw[i] - CQ[qq];
        float w = EXP2(__builtin_fmaf(-t, t, lw[i]));
        pwa[qq] += w;
        Bf[qq][i] = tobf(w);
      }
    }
    // A fragments (fixed) per quadrant + MFMA row of 4
    #pragma unroll
    for (int q = 0; q < 4; q++){
      short8 Af;
      #pragma unroll
      for (int i = 0; i < 8; i++){
        float t = uf[i] - CQ[q];
        float w = EXP2(__builtin_fmaf(-t, t, lf[i]));
        pfa[q] += w;
        Af[i] = tobf(w);
      }
      #pragma unroll
      for (int qq = 0; qq < 4; qq++)
        acc[q][qq] = __builtin_amdgcn_mfma_f32_16x16x32_bf16(Af, Bf[qq], acc[q][qq], 0, 0, 0);
    }
  }

  // marginals: shuffle-reduce (deterministic), lanes 0-15 commit as u64 fixed-point
  #pragma unroll
  for (int q = 0; q < 4; q++){
    pfa[q] += __shfl_xor(pfa[q], 16); pfa[q] += __shfl_xor(pfa[q], 32);
    pwa[q] += __shfl_xor(pwa[q], 16); pwa[q] += __shfl_xor(pwa[q], 32);
  }
  if (lane < 16){
    #pragma unroll
    for (int q = 0; q < 4; q++){
      long long vf = __builtin_llrintf(pfa[q] * FSCALE);
      long long vw = __builtin_llrintf(pwa[q] * FSCALE);
      atomicAdd(&PF64[b*64 + 16*q + r], (u64)vf);
      atomicAdd(&PW64[b*64 + 16*q + r], (u64)vw);
    }
  }

  // joint: deterministic block reduce — waves accumulate into jl in FIXED order
  __shared__ float jl[64*64];
  // C/D layout (m89-verified): col = lane&15, row = (lane>>4)*4 + reg
  #pragma unroll
  for (int w2 = 0; w2 < 4; w2++){
    if (wid == w2){
      #pragma unroll
      for (int q = 0; q < 4; q++)
        #pragma unroll
        for (int qq = 0; qq < 4; qq++)
          #pragma unroll
          for (int j = 0; j < 4; j++){
            int idx = (16*q + 4*g + j)*64 + 16*qq + r;
            float v = acc[q][qq][j];
            jl[idx] = (w2 == 0) ? v : (jl[idx] + v);
          }
    }
    __syncthreads();
  }
  // convert to u64 fixed-point, order-independent global accumulation
  for (int i = threadIdx.x; i < 4096; i += 256){
    long long v = __builtin_llrintf(jl[i] * FSCALE);
    if (v) atomicAdd(&J64[b*4096 + i], (u64)v);
  }
}

__global__ __launch_bounds__(1024) void k_final(const u64* __restrict__ J64,
                                                const u64* __restrict__ PF64,
                                                const u64* __restrict__ PW64,
                                                float* out){
  __shared__ double red[1024];
  const int tid = threadIdx.x;
  double mi_sum = 0.0;
  const double invN = 1.0 / (double)NVOX;
  for (int b = 0; b < 2; b++){
    const u64* J  = J64  + b*4096;
    const u64* PF = PF64 + b*64;
    const u64* PW = PW64 + b*64;
    double ts = 0.0;
    for (int i = tid; i < 4096; i += 1024) ts += (double)J[i] * DSCALE;
    red[tid] = ts; __syncthreads();
    for (int s = 512; s > 0; s >>= 1){ if (tid < s) red[tid] += red[tid+s]; __syncthreads(); }
    double tot = red[0] * invN;
    __syncthreads();
    double part = 0.0;
    for (int i = tid; i < 4096; i += 1024){
      int k = i >> 6, l = i & 63;
      double pj = ((double)J[i] * DSCALE * invN) / (tot + 1e-8);
      double pp = ((double)PF[k] * DSCALE * invN) * ((double)PW[l] * DSCALE * invN);
      part += pj * log((pj + 1e-8) / (pp + 1e-8));
    }
    red[tid] = part; __syncthreads();
    for (int s = 512; s > 0; s >>= 1){ if (tid < s) red[tid] += red[tid+s]; __syncthreads(); }
    mi_sum += red[0];
    __syncthreads();
  }
  if (tid == 0) out[0] = (float)(-(mi_sum * 0.5));
}

extern "C" void kernel_launch(void* const* d_in, const int* in_sizes, int n_in,
                              void* d_out, int out_size, void* d_ws, size_t ws_size,
                              hipStream_t stream) {
  const float* fixed_  = (const float*)d_in[0];
  const float* warped_ = (const float*)d_in[1];
  unsigned* wsu = (unsigned*)d_ws;
  u64* w64  = (u64*)((char*)d_ws + 64);
  u64* J64  = w64;            // 2*4096
  u64* PF64 = w64 + 8192;     // 2*64
  u64* PW64 = w64 + 8320;     // 2*64
  float* out = (float*)d_out;

  hipLaunchKernelGGL(k_init,   dim3(64),     dim3(256),  0, stream, wsu, w64);
  hipLaunchKernelGGL(k_minmax, dim3(128, 4), dim3(256),  0, stream, fixed_, warped_, wsu);
  hipLaunchKernelGGL(k_main,   dim3(GX, 2),  dim3(256),  0, stream, fixed_, warped_, J64, PF64, PW64, wsu);
  hipLaunchKernelGGL(k_final,  dim3(1),      dim3(1024), 0, stream, J64, PF64, PW64, out);
}